// Round 3
// baseline (570.355 us; speedup 1.0000x reference)
//
#include <hip/hip_runtime.h>

#define N_NODES 50000
#define N_EDGES 800000
#define F_E     128
#define HID     256
#define F_OUT   128
#define DIN     256          // F_X + F_E
#define SCAN_BLOCKS ((N_NODES + 255) / 256)
#define LDA     264          // 256 + 8 bf16 pad (528B row stride -> <=2-way bank alias, free)

typedef __attribute__((ext_vector_type(8))) short short8;   // 8 bf16 = 4 VGPR (MFMA A/B frag)
typedef __attribute__((ext_vector_type(4))) float f32x4;    // MFMA C/D frag

__device__ __forceinline__ short f2bf(float f) {            // fp32 -> bf16 RNE
    unsigned int u = __float_as_uint(f);
    u = u + 0x7FFFu + ((u >> 16) & 1u);
    return (short)(u >> 16);
}

// ---------------------------------------------------------------------------
// edge_index dtype detection (reference says int64; harness may deliver int32)
// ---------------------------------------------------------------------------
__global__ __launch_bounds__(256) void detect_kernel(const unsigned int* ei_words, int* flag) {
    __shared__ int bad;
    if (threadIdx.x == 0) bad = 0;
    __syncthreads();
    unsigned int w = ei_words[2 * threadIdx.x + 1];
    if (w != 0u) atomicOr(&bad, 1);
    __syncthreads();
    if (threadIdx.x == 0) *flag = bad ? 0 : 1;   // 1 => int64
}

__device__ __forceinline__ int load_dst(const void* ei, int e, int is64) {
    if (is64) return (int)((const long long*)ei)[N_EDGES + e];
    return ((const int*)ei)[N_EDGES + e];
}

__global__ __launch_bounds__(256) void count_kernel(const void* ei, const int* flag, int* counts) {
    int e = blockIdx.x * 256 + threadIdx.x;
    if (e >= N_EDGES) return;
    int dst = load_dst(ei, e, *flag);
    atomicAdd(&counts[dst], 1);
}

__global__ __launch_bounds__(256) void scan1_kernel(const int* counts, int* blockSums) {
    __shared__ int s[256];
    int i = blockIdx.x * 256 + threadIdx.x;
    s[threadIdx.x] = (i < N_NODES) ? counts[i] : 0;
    __syncthreads();
    for (int off = 128; off > 0; off >>= 1) {
        if (threadIdx.x < off) s[threadIdx.x] += s[threadIdx.x + off];
        __syncthreads();
    }
    if (threadIdx.x == 0) blockSums[blockIdx.x] = s[0];
}

// parallel exclusive scan of the 196 block sums (one 256-thread block)
__global__ __launch_bounds__(256) void scan2_kernel(const int* blockSums, int* blockOffs, int* offsets) {
    __shared__ int s[256];
    int tid = threadIdx.x;
    int v = (tid < SCAN_BLOCKS) ? blockSums[tid] : 0;
    s[tid] = v;
    __syncthreads();
    for (int off = 1; off < 256; off <<= 1) {
        int t = (tid >= off) ? s[tid - off] : 0;
        __syncthreads();
        s[tid] += t;
        __syncthreads();
    }
    if (tid < SCAN_BLOCKS) blockOffs[tid] = s[tid] - v;      // exclusive
    if (tid == 0) offsets[N_NODES] = s[255];                 // == N_EDGES
}

__global__ __launch_bounds__(256) void scan3_kernel(const int* counts, const int* blockOffs,
                                                    int* offsets, int* cursor) {
    __shared__ int s[256];
    int tid = threadIdx.x;
    int i = blockIdx.x * 256 + tid;
    int v = (i < N_NODES) ? counts[i] : 0;
    s[tid] = v;
    __syncthreads();
    for (int off = 1; off < 256; off <<= 1) {
        int t = (tid >= off) ? s[tid - off] : 0;
        __syncthreads();
        s[tid] += t;
        __syncthreads();
    }
    int excl = s[tid] - v + blockOffs[blockIdx.x];
    if (i < N_NODES) { offsets[i] = excl; cursor[i] = excl; }
}

__global__ __launch_bounds__(256) void fill_kernel(const void* ei, const int* flag,
                                                   int* cursor, int* edge_ids) {
    int e = blockIdx.x * 256 + threadIdx.x;
    if (e >= N_EDGES) return;
    int dst = load_dst(ei, e, *flag);
    int pos = atomicAdd(&cursor[dst], 1);
    edge_ids[pos] = e;
}

// ---------------------------------------------------------------------------
// Weight prep: W1[k][j] (256x256 f32) -> W1T[j][k] bf16 ; W2[k][j] (256x128) -> W2T[j][k] bf16
// ---------------------------------------------------------------------------
__global__ __launch_bounds__(256) void prep_w1t(const float* __restrict__ W1,
                                                unsigned short* __restrict__ W1T) {
    int idx = blockIdx.x * 256 + threadIdx.x;     // 65536
    int j = idx & 255, k = idx >> 8;
    W1T[j * 256 + k] = (unsigned short)f2bf(W1[k * 256 + j]);
}
__global__ __launch_bounds__(256) void prep_w2t(const float* __restrict__ W2,
                                                unsigned short* __restrict__ W2T) {
    int idx = blockIdx.x * 256 + threadIdx.x;     // 32768
    int j = idx & 127, k = idx >> 7;
    W2T[j * 256 + k] = (unsigned short)f2bf(W2[k * 128 + j]);
}

// ---------------------------------------------------------------------------
// FUSED: gather(scatter-mean via CSR) + bf16-MFMA MLP.
// 256 thr = 4 waves, 64 nodes/block.
// Phase 1 (per wave, 16 nodes): lane owns feature cols (2l,2l+1); stage
//   bf16(x) into A[.,0:128]; CSR-gather mean of edge_attr into A[.,128:256].
// Phase 2: H = relu(A @ W1 + b1) via mfma_16x16x32_bf16, wave owns 64 hid cols.
// Phase 3: out = H @ W2 + b2, wave owns 32 out cols.
// ---------------------------------------------------------------------------
__global__ __launch_bounds__(256) void fused_mlp_kernel(const float* __restrict__ x,
                                                        const float* __restrict__ edge_attr,
                                                        const int* __restrict__ offsets,
                                                        const int* __restrict__ edge_ids,
                                                        const unsigned short* __restrict__ W1T,
                                                        const float* __restrict__ b1,
                                                        const unsigned short* __restrict__ W2T,
                                                        const float* __restrict__ b2,
                                                        float* __restrict__ out) {
    __shared__ short A_lds[64 * LDA];    // 33 KB, inputs then h
    const int tid  = threadIdx.x;
    const int base = blockIdx.x * 64;
    const int lane = tid & 63;
    const int wid  = tid >> 6;

    // ---- phase 1: stage x + CSR gather-mean, 16 nodes per wave
    for (int nn = 0; nn < 16; ++nn) {
        const int nrow = wid * 16 + nn;
        const int node = base + nrow;
        if (node < N_NODES) {
            // x: lane reads float2 at col 2*lane (512B coalesced per row)
            const float2 xv = *(const float2*)&x[node * 128 + 2 * lane];
            *(ushort2*)&A_lds[nrow * LDA + 2 * lane] =
                make_ushort2((unsigned short)f2bf(xv.x), (unsigned short)f2bf(xv.y));
            // gather mean over this node's edges
            const int beg = offsets[node], end = offsets[node + 1];
            float ax = 0.f, ay = 0.f;
            for (int p = beg; p < end; ++p) {
                const int eid = edge_ids[p];
                const float2 v = *(const float2*)&edge_attr[eid * F_E + 2 * lane];
                ax += v.x; ay += v.y;
            }
            const float inv = 1.0f / (float)((end - beg) > 0 ? (end - beg) : 1);
            *(ushort2*)&A_lds[nrow * LDA + 128 + 2 * lane] =
                make_ushort2((unsigned short)f2bf(ax * inv), (unsigned short)f2bf(ay * inv));
        } else {
            *(ushort2*)&A_lds[nrow * LDA + 2 * lane]       = make_ushort2(0, 0);
            *(ushort2*)&A_lds[nrow * LDA + 128 + 2 * lane] = make_ushort2(0, 0);
        }
    }
    __syncthreads();

    const int lr = lane & 15;
    const int lg = lane >> 4;
    const int wc = wid * 64;

    // ---- phase 2: H[64][256] = relu(A @ W1 + b1), wave owns cols [wc, wc+64)
    f32x4 acc[4][4] = {};
#pragma unroll
    for (int kb = 0; kb < 8; ++kb) {
        short8 af[4];
#pragma unroll
        for (int m = 0; m < 4; ++m)
            af[m] = *(const short8*)&A_lds[(m * 16 + lr) * LDA + kb * 32 + lg * 8];
        short8 bf[4];
#pragma unroll
        for (int n = 0; n < 4; ++n)
            bf[n] = *(const short8*)&W1T[(wc + n * 16 + lr) * 256 + kb * 32 + lg * 8];
#pragma unroll
        for (int m = 0; m < 4; ++m)
#pragma unroll
            for (int n = 0; n < 4; ++n)
                acc[m][n] = __builtin_amdgcn_mfma_f32_16x16x32_bf16(af[m], bf[n], acc[m][n], 0, 0, 0);
    }

    float b1v[4];
#pragma unroll
    for (int n = 0; n < 4; ++n) b1v[n] = b1[wc + n * 16 + lr];

    __syncthreads();   // all waves done reading A; reuse buffer for H
#pragma unroll
    for (int m = 0; m < 4; ++m)
#pragma unroll
        for (int n = 0; n < 4; ++n)
#pragma unroll
            for (int i = 0; i < 4; ++i) {
                float h = acc[m][n][i] + b1v[n];
                h = h > 0.f ? h : 0.f;
                A_lds[(m * 16 + lg * 4 + i) * LDA + wc + n * 16 + lr] = f2bf(h);
            }
    __syncthreads();

    // ---- phase 3: out = H @ W2 + b2, wave owns cols [wid*32, wid*32+32)
    const int wc2 = wid * 32;
    f32x4 acc2[4][2] = {};
#pragma unroll
    for (int kb = 0; kb < 8; ++kb) {
        short8 af[4];
#pragma unroll
        for (int m = 0; m < 4; ++m)
            af[m] = *(const short8*)&A_lds[(m * 16 + lr) * LDA + kb * 32 + lg * 8];
        short8 bf[2];
#pragma unroll
        for (int n = 0; n < 2; ++n)
            bf[n] = *(const short8*)&W2T[(wc2 + n * 16 + lr) * 256 + kb * 32 + lg * 8];
#pragma unroll
        for (int m = 0; m < 4; ++m)
#pragma unroll
            for (int n = 0; n < 2; ++n)
                acc2[m][n] = __builtin_amdgcn_mfma_f32_16x16x32_bf16(af[m], bf[n], acc2[m][n], 0, 0, 0);
    }

    float b2v[2];
#pragma unroll
    for (int n = 0; n < 2; ++n) b2v[n] = b2[wc2 + n * 16 + lr];
#pragma unroll
    for (int m = 0; m < 4; ++m)
#pragma unroll
        for (int n = 0; n < 2; ++n)
#pragma unroll
            for (int i = 0; i < 4; ++i) {
                int node = base + m * 16 + lg * 4 + i;
                if (node < N_NODES)
                    out[node * F_OUT + wc2 + n * 16 + lr] = acc2[m][n][i] + b2v[n];
            }
}

// ---------------------------------------------------------------------------
extern "C" void kernel_launch(void* const* d_in, const int* in_sizes, int n_in,
                              void* d_out, int out_size, void* d_ws, size_t ws_size,
                              hipStream_t stream) {
    const float* x         = (const float*)d_in[0];
    const void*  ei        = d_in[1];
    const float* edge_attr = (const float*)d_in[2];
    const float* W1        = (const float*)d_in[3];
    const float* b1        = (const float*)d_in[4];
    const float* W2        = (const float*)d_in[5];
    const float* b2        = (const float*)d_in[6];
    float* out = (float*)d_out;

    char* ws = (char*)d_ws;
    size_t off = 0;
    auto alloc = [&](size_t bytes) -> void* {
        void* p = ws + off;
        off = (off + bytes + 255) & ~(size_t)255;
        return p;
    };
    int*            flag      = (int*)alloc(4);
    int*            counts    = (int*)alloc((size_t)N_NODES * 4);
    int*            offsets   = (int*)alloc((size_t)(N_NODES + 1) * 4);
    int*            cursor    = (int*)alloc((size_t)N_NODES * 4);
    int*            blockSums = (int*)alloc((size_t)SCAN_BLOCKS * 4);
    int*            blockOffs = (int*)alloc((size_t)SCAN_BLOCKS * 4);
    int*            edge_ids  = (int*)alloc((size_t)N_EDGES * 4);
    unsigned short* w1t       = (unsigned short*)alloc((size_t)DIN * HID * 2);
    unsigned short* w2t       = (unsigned short*)alloc((size_t)HID * F_OUT * 2);
    (void)ws_size; (void)in_sizes; (void)n_in; (void)out_size;

    hipMemsetAsync(counts, 0, (size_t)N_NODES * 4, stream);
    detect_kernel<<<1, 256, 0, stream>>>((const unsigned int*)ei, flag);
    prep_w1t<<<(DIN * HID) / 256, 256, 0, stream>>>(W1, w1t);
    prep_w2t<<<(HID * F_OUT) / 256, 256, 0, stream>>>(W2, w2t);
    count_kernel<<<(N_EDGES + 255) / 256, 256, 0, stream>>>(ei, flag, counts);
    scan1_kernel<<<SCAN_BLOCKS, 256, 0, stream>>>(counts, blockSums);
    scan2_kernel<<<1, 256, 0, stream>>>(blockSums, blockOffs, offsets);
    scan3_kernel<<<SCAN_BLOCKS, 256, 0, stream>>>(counts, blockOffs, offsets, cursor);
    fill_kernel<<<(N_EDGES + 255) / 256, 256, 0, stream>>>(ei, flag, cursor, edge_ids);
    fused_mlp_kernel<<<(N_NODES + 63) / 64, 256, 0, stream>>>(x, edge_attr, offsets, edge_ids,
                                                              w1t, b1, w2t, b2, out);
}

// Round 4
// 290.557 us; speedup vs baseline: 1.9630x; 1.9630x over previous
//
#include <hip/hip_runtime.h>

#define N_NODES 50000
#define N_EDGES 800000
#define F_E     128
#define HID     256
#define F_OUT   128
#define DIN     256          // F_X + F_E
#define SCAN_BLOCKS ((N_NODES + 255) / 256)
#define LDA     264          // 256 + 8 bf16 pad (528B row stride -> <=2-way bank alias, free)
#define EDEPTH  8            // edge-loop software-pipeline depth (Little's law fix)

typedef __attribute__((ext_vector_type(8))) short short8;   // 8 bf16 = 4 VGPR (MFMA A/B frag)
typedef __attribute__((ext_vector_type(4))) float f32x4;    // MFMA C/D frag

__device__ __forceinline__ short f2bf(float f) {            // fp32 -> bf16 RNE
    unsigned int u = __float_as_uint(f);
    u = u + 0x7FFFu + ((u >> 16) & 1u);
    return (short)(u >> 16);
}

// ---------------------------------------------------------------------------
// edge_index dtype detection (reference says int64; harness may deliver int32)
// ---------------------------------------------------------------------------
__global__ __launch_bounds__(256) void detect_kernel(const unsigned int* ei_words, int* flag) {
    __shared__ int bad;
    if (threadIdx.x == 0) bad = 0;
    __syncthreads();
    unsigned int w = ei_words[2 * threadIdx.x + 1];
    if (w != 0u) atomicOr(&bad, 1);
    __syncthreads();
    if (threadIdx.x == 0) *flag = bad ? 0 : 1;   // 1 => int64
}

__device__ __forceinline__ int load_dst(const void* ei, int e, int is64) {
    if (is64) return (int)((const long long*)ei)[N_EDGES + e];
    return ((const int*)ei)[N_EDGES + e];
}

__global__ __launch_bounds__(256) void count_kernel(const void* ei, const int* flag, int* counts) {
    int e = blockIdx.x * 256 + threadIdx.x;
    if (e >= N_EDGES) return;
    int dst = load_dst(ei, e, *flag);
    atomicAdd(&counts[dst], 1);
}

__global__ __launch_bounds__(256) void scan1_kernel(const int* counts, int* blockSums) {
    __shared__ int s[256];
    int i = blockIdx.x * 256 + threadIdx.x;
    s[threadIdx.x] = (i < N_NODES) ? counts[i] : 0;
    __syncthreads();
    for (int off = 128; off > 0; off >>= 1) {
        if (threadIdx.x < off) s[threadIdx.x] += s[threadIdx.x + off];
        __syncthreads();
    }
    if (threadIdx.x == 0) blockSums[blockIdx.x] = s[0];
}

// parallel exclusive scan of the 196 block sums (one 256-thread block)
__global__ __launch_bounds__(256) void scan2_kernel(const int* blockSums, int* blockOffs, int* offsets) {
    __shared__ int s[256];
    int tid = threadIdx.x;
    int v = (tid < SCAN_BLOCKS) ? blockSums[tid] : 0;
    s[tid] = v;
    __syncthreads();
    for (int off = 1; off < 256; off <<= 1) {
        int t = (tid >= off) ? s[tid - off] : 0;
        __syncthreads();
        s[tid] += t;
        __syncthreads();
    }
    if (tid < SCAN_BLOCKS) blockOffs[tid] = s[tid] - v;      // exclusive
    if (tid == 0) offsets[N_NODES] = s[255];                 // == N_EDGES
}

__global__ __launch_bounds__(256) void scan3_kernel(const int* counts, const int* blockOffs,
                                                    int* offsets, int* cursor) {
    __shared__ int s[256];
    int tid = threadIdx.x;
    int i = blockIdx.x * 256 + tid;
    int v = (i < N_NODES) ? counts[i] : 0;
    s[tid] = v;
    __syncthreads();
    for (int off = 1; off < 256; off <<= 1) {
        int t = (tid >= off) ? s[tid - off] : 0;
        __syncthreads();
        s[tid] += t;
        __syncthreads();
    }
    int excl = s[tid] - v + blockOffs[blockIdx.x];
    if (i < N_NODES) { offsets[i] = excl; cursor[i] = excl; }
}

__global__ __launch_bounds__(256) void fill_kernel(const void* ei, const int* flag,
                                                   int* cursor, int* edge_ids) {
    int e = blockIdx.x * 256 + threadIdx.x;
    if (e >= N_EDGES) return;
    int dst = load_dst(ei, e, *flag);
    int pos = atomicAdd(&cursor[dst], 1);
    edge_ids[pos] = e;
}

// ---------------------------------------------------------------------------
// Weight prep: W1[k][j] (256x256 f32) -> W1T[j][k] bf16 ; W2[k][j] (256x128) -> W2T[j][k] bf16
// ---------------------------------------------------------------------------
__global__ __launch_bounds__(256) void prep_w1t(const float* __restrict__ W1,
                                                unsigned short* __restrict__ W1T) {
    int idx = blockIdx.x * 256 + threadIdx.x;     // 65536
    int j = idx & 255, k = idx >> 8;
    W1T[j * 256 + k] = (unsigned short)f2bf(W1[k * 256 + j]);
}
__global__ __launch_bounds__(256) void prep_w2t(const float* __restrict__ W2,
                                                unsigned short* __restrict__ W2T) {
    int idx = blockIdx.x * 256 + threadIdx.x;     // 32768
    int j = idx & 127, k = idx >> 7;
    W2T[j * 256 + k] = (unsigned short)f2bf(W2[k * 128 + j]);
}

// ---------------------------------------------------------------------------
// FUSED: gather(scatter-mean via CSR) + bf16-MFMA MLP.
// 256 thr = 4 waves, 64 nodes/block.
// Phase 1 (per wave, 16 nodes): lane owns feature cols (2l,2l+1).
//   Edge loop is EDEPTH-deep pipelined: 8 clamped eid loads (broadcast, ~1
//   line), 8 INDEPENDENT 512B row loads in flight, masked accumulate.
//   48KB/CU in flight >> ~9KB needed for 6.3 TB/s (vs 6KB 1-deep before).
// Phase 2: H = relu(A @ W1 + b1) via mfma_16x16x32_bf16, wave owns 64 hid cols.
// Phase 3: out = H @ W2 + b2, wave owns 32 out cols.
// ---------------------------------------------------------------------------
__global__ __launch_bounds__(256) void fused_mlp_kernel(const float* __restrict__ x,
                                                        const float* __restrict__ edge_attr,
                                                        const int* __restrict__ offsets,
                                                        const int* __restrict__ edge_ids,
                                                        const unsigned short* __restrict__ W1T,
                                                        const float* __restrict__ b1,
                                                        const unsigned short* __restrict__ W2T,
                                                        const float* __restrict__ b2,
                                                        float* __restrict__ out) {
    __shared__ short A_lds[64 * LDA];    // 33 KB, inputs then h
    const int tid  = threadIdx.x;
    const int base = blockIdx.x * 64;
    const int lane = tid & 63;
    const int wid  = tid >> 6;

    // ---- phase 1: stage x + CSR gather-mean, 16 nodes per wave
    for (int nn = 0; nn < 16; ++nn) {
        const int nrow = wid * 16 + nn;
        const int node = base + nrow;
        if (node < N_NODES) {
            // x: lane reads float2 at col 2*lane (512B coalesced per row)
            const float2 xv = *(const float2*)&x[node * 128 + 2 * lane];
            *(ushort2*)&A_lds[nrow * LDA + 2 * lane] =
                make_ushort2((unsigned short)f2bf(xv.x), (unsigned short)f2bf(xv.y));
            // gather mean over this node's edges, EDEPTH-deep pipelined
            const int beg = offsets[node], end = offsets[node + 1];
            float ax = 0.f, ay = 0.f;
            for (int p = beg; p < end; p += EDEPTH) {
                int eid[EDEPTH];
#pragma unroll
                for (int j = 0; j < EDEPTH; ++j) {
                    int q = p + j;
                    q = q < end - 1 ? q : end - 1;        // clamp (re-read -> L1 hit)
                    eid[j] = edge_ids[q];
                }
                float2 v[EDEPTH];
#pragma unroll
                for (int j = 0; j < EDEPTH; ++j)
                    v[j] = *(const float2*)&edge_attr[(size_t)eid[j] * F_E + 2 * lane];
#pragma unroll
                for (int j = 0; j < EDEPTH; ++j) {
                    if (p + j < end) { ax += v[j].x; ay += v[j].y; }   // wave-uniform mask
                }
            }
            const float inv = 1.0f / (float)((end - beg) > 0 ? (end - beg) : 1);
            *(ushort2*)&A_lds[nrow * LDA + 128 + 2 * lane] =
                make_ushort2((unsigned short)f2bf(ax * inv), (unsigned short)f2bf(ay * inv));
        } else {
            *(ushort2*)&A_lds[nrow * LDA + 2 * lane]       = make_ushort2(0, 0);
            *(ushort2*)&A_lds[nrow * LDA + 128 + 2 * lane] = make_ushort2(0, 0);
        }
    }
    __syncthreads();

    const int lr = lane & 15;
    const int lg = lane >> 4;
    const int wc = wid * 64;

    // ---- phase 2: H[64][256] = relu(A @ W1 + b1), wave owns cols [wc, wc+64)
    f32x4 acc[4][4] = {};
#pragma unroll
    for (int kb = 0; kb < 8; ++kb) {
        short8 af[4];
#pragma unroll
        for (int m = 0; m < 4; ++m)
            af[m] = *(const short8*)&A_lds[(m * 16 + lr) * LDA + kb * 32 + lg * 8];
        short8 bf[4];
#pragma unroll
        for (int n = 0; n < 4; ++n)
            bf[n] = *(const short8*)&W1T[(wc + n * 16 + lr) * 256 + kb * 32 + lg * 8];
#pragma unroll
        for (int m = 0; m < 4; ++m)
#pragma unroll
            for (int n = 0; n < 4; ++n)
                acc[m][n] = __builtin_amdgcn_mfma_f32_16x16x32_bf16(af[m], bf[n], acc[m][n], 0, 0, 0);
    }

    float b1v[4];
#pragma unroll
    for (int n = 0; n < 4; ++n) b1v[n] = b1[wc + n * 16 + lr];

    __syncthreads();   // all waves done reading A; reuse buffer for H
#pragma unroll
    for (int m = 0; m < 4; ++m)
#pragma unroll
        for (int n = 0; n < 4; ++n)
#pragma unroll
            for (int i = 0; i < 4; ++i) {
                float h = acc[m][n][i] + b1v[n];
                h = h > 0.f ? h : 0.f;
                A_lds[(m * 16 + lg * 4 + i) * LDA + wc + n * 16 + lr] = f2bf(h);
            }
    __syncthreads();

    // ---- phase 3: out = H @ W2 + b2, wave owns cols [wid*32, wid*32+32)
    const int wc2 = wid * 32;
    f32x4 acc2[4][2] = {};
#pragma unroll
    for (int kb = 0; kb < 8; ++kb) {
        short8 af[4];
#pragma unroll
        for (int m = 0; m < 4; ++m)
            af[m] = *(const short8*)&A_lds[(m * 16 + lr) * LDA + kb * 32 + lg * 8];
        short8 bf[2];
#pragma unroll
        for (int n = 0; n < 2; ++n)
            bf[n] = *(const short8*)&W2T[(wc2 + n * 16 + lr) * 256 + kb * 32 + lg * 8];
#pragma unroll
        for (int m = 0; m < 4; ++m)
#pragma unroll
            for (int n = 0; n < 2; ++n)
                acc2[m][n] = __builtin_amdgcn_mfma_f32_16x16x32_bf16(af[m], bf[n], acc2[m][n], 0, 0, 0);
    }

    float b2v[2];
#pragma unroll
    for (int n = 0; n < 2; ++n) b2v[n] = b2[wc2 + n * 16 + lr];
#pragma unroll
    for (int m = 0; m < 4; ++m)
#pragma unroll
        for (int n = 0; n < 2; ++n)
#pragma unroll
            for (int i = 0; i < 4; ++i) {
                int node = base + m * 16 + lg * 4 + i;
                if (node < N_NODES)
                    out[node * F_OUT + wc2 + n * 16 + lr] = acc2[m][n][i] + b2v[n];
            }
}

// ---------------------------------------------------------------------------
extern "C" void kernel_launch(void* const* d_in, const int* in_sizes, int n_in,
                              void* d_out, int out_size, void* d_ws, size_t ws_size,
                              hipStream_t stream) {
    const float* x         = (const float*)d_in[0];
    const void*  ei        = d_in[1];
    const float* edge_attr = (const float*)d_in[2];
    const float* W1        = (const float*)d_in[3];
    const float* b1        = (const float*)d_in[4];
    const float* W2        = (const float*)d_in[5];
    const float* b2        = (const float*)d_in[6];
    float* out = (float*)d_out;

    char* ws = (char*)d_ws;
    size_t off = 0;
    auto alloc = [&](size_t bytes) -> void* {
        void* p = ws + off;
        off = (off + bytes + 255) & ~(size_t)255;
        return p;
    };
    int*            flag      = (int*)alloc(4);
    int*            counts    = (int*)alloc((size_t)N_NODES * 4);
    int*            offsets   = (int*)alloc((size_t)(N_NODES + 1) * 4);
    int*            cursor    = (int*)alloc((size_t)N_NODES * 4);
    int*            blockSums = (int*)alloc((size_t)SCAN_BLOCKS * 4);
    int*            blockOffs = (int*)alloc((size_t)SCAN_BLOCKS * 4);
    int*            edge_ids  = (int*)alloc((size_t)N_EDGES * 4);
    unsigned short* w1t       = (unsigned short*)alloc((size_t)DIN * HID * 2);
    unsigned short* w2t       = (unsigned short*)alloc((size_t)HID * F_OUT * 2);
    (void)ws_size; (void)in_sizes; (void)n_in; (void)out_size;

    hipMemsetAsync(counts, 0, (size_t)N_NODES * 4, stream);
    detect_kernel<<<1, 256, 0, stream>>>((const unsigned int*)ei, flag);
    prep_w1t<<<(DIN * HID) / 256, 256, 0, stream>>>(W1, w1t);
    prep_w2t<<<(HID * F_OUT) / 256, 256, 0, stream>>>(W2, w2t);
    count_kernel<<<(N_EDGES + 255) / 256, 256, 0, stream>>>(ei, flag, counts);
    scan1_kernel<<<SCAN_BLOCKS, 256, 0, stream>>>(counts, blockSums);
    scan2_kernel<<<1, 256, 0, stream>>>(blockSums, blockOffs, offsets);
    scan3_kernel<<<SCAN_BLOCKS, 256, 0, stream>>>(counts, blockOffs, offsets, cursor);
    fill_kernel<<<(N_EDGES + 255) / 256, 256, 0, stream>>>(ei, flag, cursor, edge_ids);
    fused_mlp_kernel<<<(N_NODES + 63) / 64, 256, 0, stream>>>(x, edge_attr, offsets, edge_ids,
                                                              w1t, b1, w2t, b2, out);
}